// Round 9
// baseline (849.590 us; speedup 1.0000x reference)
//
#include <hip/hip_runtime.h>

// Dual_Quantize2: joint VQ over concatenated (lr,hr) features, dim 512, 1024 codes.
//   prep:    codebooks -> pre-swizzled bf16 hi/lo blobs, transposed gather copies,
//            c_e = 0.5*||E||^2, zero rescue counter.
//   asplit:  inputs -> pre-swizzled bf16 hi/lo blobs (needs 144MB ws, else inline).
//   gemm:    bf16x3 MFMA GEMM; per-(row, half-block) TOP-2 keys, 16 race-free groups.
//   select:  merge 16 groups' top-2 -> winner + gap; gap < DELTA -> rescue list.
//   rescue:  re-score ambiguous rows EMULATING numpy-float32 semantics:
//              d32 = fl(fl(A - fl(2*m)) + sE)
//              A  = np pairwise fp32 sum of f^2 (AVX512 block emulation),
//              sE = sequential fp32 accumulation over k (np axis-0 reduce),
//              m  = fp64 dot rounded to fp32 (~BLAS sgemm),
//            ties -> lowest index. (Round-8 evidence: exact-fp64 argmin still
//            mismatched one row by 136 -> the np ref is fp32-quantized; we must
//            match ITS rounding, not the true argmin.)
//   epi/fin: codebook gather -> quantize outputs, embed_ind, deterministic diffs.

#define DIM 256
#define NEMB 1024
#define DELTA 4.0e-3f
#define RESCUE_CAP 8192
#define RCHUNK 16

typedef __attribute__((ext_vector_type(8))) short short8;
typedef __attribute__((ext_vector_type(4))) float f32x4;

__device__ __forceinline__ unsigned short f2bf(float f) {
  unsigned u = __float_as_uint(f);
  u += 0x7fffu + ((u >> 16) & 1u);   // RNE
  return (unsigned short)(u >> 16);
}
__device__ __forceinline__ float bf2f(unsigned short h) {
  return __uint_as_float(((unsigned)h) << 16);
}
__device__ __forceinline__ float wave_sum(float v) {
#pragma unroll
  for (int m = 32; m >= 1; m >>= 1) v += __shfl_xor(v, m, 64);
  return v;
}
__device__ __forceinline__ int swz(int row, int byteoff) {
  return row * 128 + (byteoff ^ ((row & 7) << 4));
}
__device__ __forceinline__ float unpack_score(unsigned h) {
  return __uint_as_float((h & 0x80000000u) ? (h ^ 0x80000000u) : ~h);
}

typedef __attribute__((address_space(1))) const unsigned int GAS;
typedef __attribute__((address_space(3))) unsigned int LAS;
__device__ __forceinline__ void gload16(const void* g, void* l) {
  __builtin_amdgcn_global_load_lds((GAS*)g, (LAS*)l, 16, 0, 0);
}

// numpy pairwise fp32 sum of squares for one 128-block, AVX512 emulation:
// 4 accumulators x 16 lanes (r0..r3), one add pass, r=(r0+r1)+(r2+r3),
// then _mm512_reduce_add_ps lane tree: (i,i+8) -> (i,i+4) -> (i,i+2) -> (0,1).
__device__ float np_sq128_avx512(const float* f) {
  float s[16];
#pragma unroll
  for (int l = 0; l < 16; ++l) {
    const float r0 = __fadd_rn(__fmul_rn(f[l],      f[l]),      __fmul_rn(f[64 + l],  f[64 + l]));
    const float r1 = __fadd_rn(__fmul_rn(f[16 + l], f[16 + l]), __fmul_rn(f[80 + l],  f[80 + l]));
    const float r2 = __fadd_rn(__fmul_rn(f[32 + l], f[32 + l]), __fmul_rn(f[96 + l],  f[96 + l]));
    const float r3 = __fadd_rn(__fmul_rn(f[48 + l], f[48 + l]), __fmul_rn(f[112 + l], f[112 + l]));
    s[l] = __fadd_rn(__fadd_rn(r0, r1), __fadd_rn(r2, r3));
  }
  float u[8], v[4];
#pragma unroll
  for (int i = 0; i < 8; ++i) u[i] = __fadd_rn(s[i], s[i + 8]);
#pragma unroll
  for (int i = 0; i < 4; ++i) v[i] = __fadd_rn(u[i], u[i + 4]);
  return __fadd_rn(__fadd_rn(v[0], v[2]), __fadd_rn(v[1], v[3]));
}
// n=512: recursive split 256|256 -> 128-blocks: A = (B0+B1)+(B2+B3)
__device__ float np_sumsq512(const float* f) {
  const float b0 = np_sq128_avx512(f);
  const float b1 = np_sq128_avx512(f + 128);
  const float b2 = np_sq128_avx512(f + 256);
  const float b3 = np_sq128_avx512(f + 384);
  return __fadd_rn(__fadd_rn(b0, b1), __fadd_rn(b2, b3));
}

// ---------------------------------------------------------------- prep (1024 blk)
__global__ __launch_bounds__(256)
void prep_kernel(const float* __restrict__ embed_lr, const float* __restrict__ embed_hr,
                 short* __restrict__ Bs_hi, short* __restrict__ Bs_lo,
                 float* __restrict__ eT_lr, float* __restrict__ eT_hr,
                 float* __restrict__ cvec, int* __restrict__ rescue_count)
{
  const int e = blockIdx.x;   // codebook column 0..1023
  const int t = threadIdx.x;  // dim 0..255
  const float vlr = embed_lr[t * NEMB + e];
  const float vhr = embed_hr[t * NEMB + e];
  const unsigned short hl = f2bf(vlr); const unsigned short ll = f2bf(vlr - bf2f(hl));
  const unsigned short hh = f2bf(vhr); const unsigned short lh = f2bf(vhr - bf2f(hh));
  const int bn = e >> 7, row = e & 127;
  const int kk = (t & 63) * 2;
  const int off = row * 128 + (kk ^ ((row & 7) << 4));
  const size_t blob_lr = (size_t)(bn * 8 + (t >> 6)) * 16384 + off;       // k = t
  const size_t blob_hr = (size_t)(bn * 8 + 4 + (t >> 6)) * 16384 + off;   // k = 256+t
  *(short*)((char*)Bs_hi + blob_lr) = (short)hl;
  *(short*)((char*)Bs_lo + blob_lr) = (short)ll;
  *(short*)((char*)Bs_hi + blob_hr) = (short)hh;
  *(short*)((char*)Bs_lo + blob_hr) = (short)lh;
  eT_lr[e * DIM + t] = vlr;  eT_hr[e * DIM + t] = vhr;

  const float s = wave_sum(vlr * vlr + vhr * vhr);
  __shared__ float red[4];
  if ((t & 63) == 0) red[t >> 6] = s;
  __syncthreads();
  if (t == 0) cvec[e] = 0.5f * (red[0] + red[1] + red[2] + red[3]);
  if (e == 0 && t == 0) *rescue_count = 0;
}

// ------------------------------------------------- asplit (M/128 * 8 blk, fast path)
__global__ __launch_bounds__(256)
void asplit_kernel(const float* __restrict__ in_hr, const float* __restrict__ in_lr,
                   short* __restrict__ Ah, short* __restrict__ Al)
{
  const int bm = blockIdx.x >> 3, kc = blockIdx.x & 7;
  const int k0 = kc * 64;
  const float* asrc = (k0 < 256) ? (in_lr + k0) : (in_hr + (k0 - 256));
  char* dh = (char*)Ah + (size_t)blockIdx.x * 16384;
  char* dl = (char*)Al + (size_t)blockIdx.x * 16384;
  const int tid = threadIdx.x;
#pragma unroll
  for (int i = 0; i < 8; ++i) {
    const int idx = i * 256 + tid;
    const int row = idx >> 4;
    const int kq  = idx & 15;
    const float4 v = *(const float4*)(asrc + (size_t)(bm * 128 + row) * DIM + kq * 4);
    ushort4 hv, lv;
    hv.x = f2bf(v.x); lv.x = f2bf(v.x - bf2f(hv.x));
    hv.y = f2bf(v.y); lv.y = f2bf(v.y - bf2f(hv.y));
    hv.z = f2bf(v.z); lv.z = f2bf(v.z - bf2f(hv.z));
    hv.w = f2bf(v.w); lv.w = f2bf(v.w - bf2f(hv.w));
    const int off = swz(row, kq * 8);
    *(ushort4*)(dh + off) = hv;
    *(ushort4*)(dl + off) = lv;
  }
}

// ------------------------------------------------------------ gemm+top2 (4096 blk)
template<bool PRESPLIT>
__global__ __launch_bounds__(256, 2)
void gemm_argmin_kernel(const float* __restrict__ in_hr, const float* __restrict__ in_lr,
                        const short* __restrict__ Ah, const short* __restrict__ Al,
                        const short* __restrict__ Bs_hi, const short* __restrict__ Bs_lo,
                        const float* __restrict__ cvec,
                        unsigned long long* __restrict__ top1,
                        unsigned long long* __restrict__ top2, int M)
{
  __shared__ unsigned char smem[65536];  // Ah | Al | Bh | Bl planes, 16KB each
  const int tid = threadIdx.x;
  const int bn = blockIdx.x;
  const int bm = blockIdx.y;
  const int lane = tid & 63, w = tid >> 6;
  const int wm = w >> 1, wn = w & 1;
  const int l15 = lane & 15, l4 = lane >> 4;

  f32x4 acc[4][4] = {};

  for (int kc = 0; kc < 8; ++kc) {
    __syncthreads();
    const size_t bof = (size_t)(bn * 8 + kc) * 16384;
    if (PRESPLIT) {
      const size_t aof = (size_t)(bm * 8 + kc) * 16384;
#pragma unroll
      for (int i = 0; i < 4; ++i) {
        const int seg = (w * 4 + i) * 1024;
        const int gsl = seg + lane * 16;
        gload16((const char*)Ah + aof + gsl,    smem + seg);
        gload16((const char*)Al + aof + gsl,    smem + 16384 + seg);
        gload16((const char*)Bs_hi + bof + gsl, smem + 32768 + seg);
        gload16((const char*)Bs_lo + bof + gsl, smem + 49152 + seg);
      }
    } else {
#pragma unroll
      for (int i = 0; i < 4; ++i) {
        const int seg = (w * 4 + i) * 1024;
        const int gsl = seg + lane * 16;
        gload16((const char*)Bs_hi + bof + gsl, smem + 32768 + seg);
        gload16((const char*)Bs_lo + bof + gsl, smem + 49152 + seg);
      }
      const int k0 = kc * 64;
      const float* asrc = (k0 < 256) ? (in_lr + k0) : (in_hr + (k0 - 256));
#pragma unroll
      for (int i = 0; i < 8; ++i) {
        const int idx = i * 256 + tid;
        const int row = idx >> 4;
        const int kq  = idx & 15;
        const float4 v = *(const float4*)(asrc + (size_t)(bm * 128 + row) * DIM + kq * 4);
        ushort4 hv, lv;
        hv.x = f2bf(v.x); lv.x = f2bf(v.x - bf2f(hv.x));
        hv.y = f2bf(v.y); lv.y = f2bf(v.y - bf2f(hv.y));
        hv.z = f2bf(v.z); lv.z = f2bf(v.z - bf2f(hv.z));
        hv.w = f2bf(v.w); lv.w = f2bf(v.w - bf2f(hv.w));
        const int off = swz(row, kq * 8);
        *(ushort4*)(smem + off)         = hv;
        *(ushort4*)(smem + 16384 + off) = lv;
      }
    }
    __syncthreads();
#pragma unroll
    for (int s = 0; s < 2; ++s) {
      short8 ah[4], al[4], bh[4], bl[4];
#pragma unroll
      for (int f = 0; f < 4; ++f) {
        const int aoff = swz(wm * 64 + f * 16 + l15, s * 64 + l4 * 16);
        ah[f] = *(const short8*)(smem + aoff);
        al[f] = *(const short8*)(smem + 16384 + aoff);
        const int boff = swz(wn * 64 + f * 16 + l15, s * 64 + l4 * 16);
        bh[f] = *(const short8*)(smem + 32768 + boff);
        bl[f] = *(const short8*)(smem + 49152 + boff);
      }
#pragma unroll
      for (int mf = 0; mf < 4; ++mf)
#pragma unroll
        for (int nf = 0; nf < 4; ++nf) {
          acc[mf][nf] = __builtin_amdgcn_mfma_f32_16x16x32_bf16(ah[mf], bh[nf], acc[mf][nf], 0, 0, 0);
          acc[mf][nf] = __builtin_amdgcn_mfma_f32_16x16x32_bf16(ah[mf], bl[nf], acc[mf][nf], 0, 0, 0);
          acc[mf][nf] = __builtin_amdgcn_mfma_f32_16x16x32_bf16(al[mf], bh[nf], acc[mf][nf], 0, 0, 0);
        }
    }
  }

  // per-(row, half-block) TOP-2; 16 groups of 64 codes -> no write sharing
  const int grp = bn * 2 + wn;
  float cv[4];
#pragma unroll
  for (int nf = 0; nf < 4; ++nf) cv[nf] = cvec[bn * 128 + wn * 64 + nf * 16 + l15];
#pragma unroll
  for (int mf = 0; mf < 4; ++mf) {
#pragma unroll
    for (int j = 0; j < 4; ++j) {
      unsigned long long m1 = ~0ULL, m2 = ~0ULL;
#pragma unroll
      for (int nf = 0; nf < 4; ++nf) {
        const int e = bn * 128 + wn * 64 + nf * 16 + l15;
        const float score = cv[nf] - acc[mf][nf][j];
        unsigned u = __float_as_uint(score);
        u = (u & 0x80000000u) ? ~u : (u | 0x80000000u);
        const unsigned long long key = ((unsigned long long)u << 32) | (unsigned long long)(unsigned)e;
        if (key < m1) { m2 = m1; m1 = key; } else if (key < m2) m2 = key;
      }
#pragma unroll
      for (int m = 1; m < 16; m <<= 1) {
        const unsigned long long o1 = __shfl_xor(m1, m, 64);
        const unsigned long long o2 = __shfl_xor(m2, m, 64);
        const unsigned long long lo = m1 < o1 ? m1 : o1;
        const unsigned long long hi = m1 < o1 ? o1 : m1;
        const unsigned long long mn2 = m2 < o2 ? m2 : o2;
        m1 = lo;
        m2 = hi < mn2 ? hi : mn2;
      }
      if (l15 == 0) {
        const int grow = bm * 128 + wm * 64 + mf * 16 + l4 * 4 + j;
        top1[(size_t)grp * M + grow] = m1;
        top2[(size_t)grp * M + grow] = m2;
      }
    }
  }
}

// ------------------------------------------------------- select (M/256 blk)
__global__ __launch_bounds__(256)
void select_kernel(const unsigned long long* __restrict__ top1,
                   const unsigned long long* __restrict__ top2,
                   unsigned long long* __restrict__ keys,
                   int* __restrict__ rescue_rows, int* __restrict__ rescue_count, int M)
{
  const int r = blockIdx.x * 256 + threadIdx.x;
  unsigned long long m1 = ~0ULL, m2 = ~0ULL;
  int gs = 0;
#pragma unroll
  for (int g = 0; g < 16; ++g) {
    const unsigned long long k = top1[(size_t)g * M + r];
    if (k < m1) { m2 = m1; m1 = k; gs = g; } else if (k < m2) m2 = k;
  }
  const unsigned long long t2w = top2[(size_t)gs * M + r];
  if (t2w < m2) m2 = t2w;
  keys[r] = m1;
  const float s1 = unpack_score((unsigned)(m1 >> 32));
  const float s2 = unpack_score((unsigned)(m2 >> 32));
  if (s2 - s1 < DELTA) {
    const int i = atomicAdd(rescue_count, 1);
    if (i < RESCUE_CAP) rescue_rows[i] = r;
  }
}

// ------------------- rescue: numpy-float32-emulated re-score (16 rows/block)
__global__ __launch_bounds__(256)
void rescue_kernel(const float* __restrict__ in_hr, const float* __restrict__ in_lr,
                   const float* __restrict__ embed_lr, const float* __restrict__ embed_hr,
                   const int* __restrict__ rescue_rows, const int* __restrict__ rescue_count,
                   unsigned long long* __restrict__ keys)
{
  __shared__ float F[RCHUNK][512];   // 32KB chunk rows (concat [lr, hr])
  __shared__ float Arow[RCHUNK];     // np-emulated fp32 ||f||^2 per row
  __shared__ float sE[NEMB];         // np-emulated fp32 ||E||^2 per code (4KB)
  __shared__ float bdl[256];
  __shared__ int   bel[256];
  __shared__ int   rown[RCHUNK];
  const int t = threadIdx.x;

  // sE: np.sum(E*E, axis=0) = SEQUENTIAL fp32 accumulation over concat rows
  // (axis-0 reduce is row-by-row regardless of SIMD -> exactly replicable)
#pragma unroll
  for (int c = 0; c < 4; ++c) {
    const int e = c * 256 + t;
    float s = 0.f;
    for (int k = 0; k < 256; ++k) {
      const float v = embed_lr[k * NEMB + e];
      s = __fadd_rn(s, __fmul_rn(v, v));
    }
    for (int k = 0; k < 256; ++k) {
      const float v = embed_hr[k * NEMB + e];
      s = __fadd_rn(s, __fmul_rn(v, v));
    }
    sE[e] = s;
  }
  __syncthreads();

  int n = *rescue_count; if (n > RESCUE_CAP) n = RESCUE_CAP;
  for (int base = blockIdx.x * RCHUNK; base < n; base += gridDim.x * RCHUNK) {
    const int nr = min(RCHUNK, n - base);
    if (t < nr) rown[t] = rescue_rows[base + t];
    __syncthreads();
    for (int i = t; i < nr * 512; i += 256) {
      const int r = i >> 9, k = i & 511;
      F[r][k] = (k < 256) ? in_lr[(size_t)rown[r] * DIM + k]
                          : in_hr[(size_t)rown[r] * DIM + (k - 256)];
    }
    __syncthreads();
    if (t < nr) Arow[t] = np_sumsq512(F[t]);   // np pairwise fp32 (AVX512 emu)
    __syncthreads();

    float bd[RCHUNK]; int be_[RCHUNK];
#pragma unroll
    for (int r = 0; r < RCHUNK; ++r) { bd[r] = 3.4e38f; be_[r] = 0; }
    for (int c = 0; c < 4; ++c) {      // thread t owns codes c*256+t (coalesced)
      const int e = c * 256 + t;
      double md[RCHUNK];
#pragma unroll
      for (int r = 0; r < RCHUNK; ++r) md[r] = 0.0;
      for (int k = 0; k < 256; ++k) {
        const double el = (double)embed_lr[k * NEMB + e];
#pragma unroll
        for (int r = 0; r < RCHUNK; ++r) md[r] += (double)F[r][k] * el;
      }
      for (int k = 0; k < 256; ++k) {
        const double eh = (double)embed_hr[k * NEMB + e];
#pragma unroll
        for (int r = 0; r < RCHUNK; ++r) md[r] += (double)F[r][256 + k] * eh;
      }
      const float se = sE[e];
#pragma unroll
      for (int r = 0; r < RCHUNK; ++r) {
        const float t2m = (float)(2.0 * md[r]);     // fl32(2m) ~ BLAS sgemm
        const float x   = __fadd_rn(Arow[r], -t2m); // fl(A - 2m)
        const float d   = __fadd_rn(x, se);         // fl(... + sE)
        if (d < bd[r]) { bd[r] = d; be_[r] = e; }   // e ascends -> ties keep low e
      }
    }
    // per-row reduce (uniform nr; static r with uniform guard), ties -> lowest e
#pragma unroll
    for (int r = 0; r < RCHUNK; ++r) {
      if (r < nr) {
        bdl[t] = bd[r]; bel[t] = be_[r];
        __syncthreads();
        for (int s = 128; s > 0; s >>= 1) {
          if (t < s) {
            if (bdl[t + s] < bdl[t] || (bdl[t + s] == bdl[t] && bel[t + s] < bel[t])) {
              bdl[t] = bdl[t + s]; bel[t] = bel[t + s];
            }
          }
          __syncthreads();
        }
        if (t == 0) keys[rown[r]] = (unsigned long long)(unsigned)bel[0];
        __syncthreads();
      }
    }
  }
}

// ---------------------------------------------------------------- epilogue/finalize
__global__ __launch_bounds__(256)
void epilogue_kernel(const float* __restrict__ in_hr, const float* __restrict__ in_lr,
                     const float* __restrict__ eT_lr, const float* __restrict__ eT_hr,
                     const unsigned long long* __restrict__ keys,
                     float* __restrict__ out, float* __restrict__ part_hr,
                     float* __restrict__ part_lr, int M)
{
  const int t = threadIdx.x;
  const int n0 = blockIdx.x * 16;
  const size_t Q = (size_t)M * DIM;
  float sh = 0.f, sl = 0.f;
  for (int r = 0; r < 16; ++r) {
    const int n = n0 + r;
    const unsigned e = (unsigned)keys[n];
    const float qh = eT_hr[(size_t)e * DIM + t];
    const float ql = eT_lr[(size_t)e * DIM + t];
    const float ih = in_hr[(size_t)n * DIM + t];
    const float il = in_lr[(size_t)n * DIM + t];
    out[(size_t)n * DIM + t]     = qh;
    out[Q + (size_t)n * DIM + t] = ql;
    const float dh = qh - ih, dl = ql - il;
    sh += dh * dh; sl += dl * dl;
  }
  sh = wave_sum(sh); sl = wave_sum(sl);
  __shared__ float rh[4], rl[4];
  if ((t & 63) == 0) { rh[t >> 6] = sh; rl[t >> 6] = sl; }
  __syncthreads();
  if (t == 0) {
    part_hr[blockIdx.x] = rh[0] + rh[1] + rh[2] + rh[3];
    part_lr[blockIdx.x] = rl[0] + rl[1] + rl[2] + rl[3];
  }
  if (t < 16) {
    const int n = n0 + t;
    const float fe = (float)(unsigned)keys[n];
    out[2 * Q + 2 + n]     = fe;  // embed_ind
    out[2 * Q + 2 + M + n] = fe;  // embed_ind (returned twice)
  }
}

__global__ __launch_bounds__(256)
void finalize_kernel(const float* __restrict__ part_hr, const float* __restrict__ part_lr,
                     float* __restrict__ out, int M)
{
  const int t = threadIdx.x;
  const int P = M / 16;
  double sh = 0.0, sl = 0.0;
  for (int i = t; i < P; i += 256) { sh += (double)part_hr[i]; sl += (double)part_lr[i]; }
  __shared__ double dh[256], dl[256];
  dh[t] = sh; dl[t] = sl;
  __syncthreads();
  for (int s = 128; s > 0; s >>= 1) {
    if (t < s) { dh[t] += dh[t + s]; dl[t] += dl[t + s]; }
    __syncthreads();
  }
  if (t == 0) {
    const size_t Q = (size_t)M * DIM;
    out[2 * Q]     = (float)(dh[0] / (double)Q);  // diff_hr
    out[2 * Q + 1] = (float)(dl[0] / (double)Q);  // diff_lr
  }
}

extern "C" void kernel_launch(void* const* d_in, const int* in_sizes, int n_in,
                              void* d_out, int out_size, void* d_ws, size_t ws_size,
                              hipStream_t stream)
{
  const float* in_hr    = (const float*)d_in[0];
  const float* in_lr    = (const float*)d_in[1];
  const float* embed_lr = (const float*)d_in[2];
  const float* embed_hr = (const float*)d_in[3];
  float* out = (float*)d_out;
  const int M = in_sizes[0] / DIM;  // 65536 rows

  // ws low region (< 5.5MB — footprint round 2 proved safe):
  unsigned char* ws = (unsigned char*)d_ws;
  short* Bs_hi = (short*)(ws);
  short* Bs_lo = (short*)(ws + (1u << 20));
  float* eT_lr = (float*)(ws + (2u << 20));
  float* eT_hr = (float*)(ws + (3u << 20));
  float* cvec  = (float*)(ws + (4u << 20));
  unsigned long long* keys = (unsigned long long*)(ws + (4u << 20) + 8192);
  int* rescue_count = (int*)(ws + (4u << 20) + 8192 + (size_t)M * 8);
  int* rescue_rows  = rescue_count + 16;
  float* part_hr    = (float*)(rescue_rows + RESCUE_CAP);
  float* part_lr    = part_hr + (M / 16);
  // top1/top2 (16MB, 16 groups) in d_out's quantize region: gemm writes ->
  // select reads -> epilogue fully overwrites.
  unsigned long long* top1 = (unsigned long long*)d_out;
  unsigned long long* top2 = top1 + (size_t)16 * M;
  short* Ah = (short*)(ws + (16u << 20));
  short* Al = (short*)(ws + (80u << 20));
  const bool presplit = ws_size >= (144u << 20);

  prep_kernel<<<NEMB, 256, 0, stream>>>(embed_lr, embed_hr, Bs_hi, Bs_lo,
                                        eT_lr, eT_hr, cvec, rescue_count);
  if (presplit) {
    asplit_kernel<<<(M / 128) * 8, 256, 0, stream>>>(in_hr, in_lr, Ah, Al);
    gemm_argmin_kernel<true><<<dim3(NEMB / 128, M / 128), 256, 0, stream>>>(
        in_hr, in_lr, Ah, Al, Bs_hi, Bs_lo, cvec, top1, top2, M);
  } else {
    gemm_argmin_kernel<false><<<dim3(NEMB / 128, M / 128), 256, 0, stream>>>(
        in_hr, in_lr, Ah, Al, Bs_hi, Bs_lo, cvec, top1, top2, M);
  }
  select_kernel<<<M / 256, 256, 0, stream>>>(top1, top2, keys, rescue_rows,
                                             rescue_count, M);
  rescue_kernel<<<64, 256, 0, stream>>>(in_hr, in_lr, embed_lr, embed_hr,
                                        rescue_rows, rescue_count, keys);
  epilogue_kernel<<<M / 16, 256, 0, stream>>>(in_hr, in_lr, eT_lr, eT_hr, keys,
                                              out, part_hr, part_lr, M);
  finalize_kernel<<<1, 256, 0, stream>>>(part_hr, part_lr, out, M);
}